// Round 7
// baseline (241.427 us; speedup 1.0000x reference)
//
#include <hip/hip_runtime.h>
#include <cstddef>
#include <cstdint>

#define SCALE_WEIGHT 0.70710678118654752440f

static constexpr int B_ = 8, C_ = 512, T_ = 2048, S_ = 2048;
static constexpr size_t BCT_ = (size_t)B_ * C_ * T_;   // 8.4M  (ctx region elems)
static constexpr size_t BTS_ = (size_t)B_ * T_ * S_;   // 33.5M (attn region elems)

typedef _Float16 half_t;
typedef half_t half8  __attribute__((ext_vector_type(8)));
typedef half_t half4v __attribute__((ext_vector_type(4)));
typedef float  floatx4 __attribute__((ext_vector_type(4)));

// async global->LDS, 16B per lane. LDS dest = wave-uniform base + lane*16.
__device__ __forceinline__ void gload_lds16(const void* g, void* l) {
    __builtin_amdgcn_global_load_lds(
        (const __attribute__((address_space(1))) void*)g,
        (__attribute__((address_space(3))) void*)l, 16, 0, 0);
}

// ---------------------------------------------------------------------------
// merged pre-pass: z<16 -> 64x64 transpose+convert of x/top; z==16 -> flat
// f32->f16 convert of comb and W (grid-stride over the plane's 256 blocks).
// ---------------------------------------------------------------------------
__global__ __launch_bounds__(256) void pre_kernel(
    const float* __restrict__ x, const float* __restrict__ top,
    const float* __restrict__ comb, const float* __restrict__ W,
    half_t* __restrict__ xT, half_t* __restrict__ topT,
    half_t* __restrict__ combh, half_t* __restrict__ Wh)
{
    const int z = blockIdx.z;
    if (z < 16) {
        __shared__ float tile[64][65];
        const float* in = (z < 8) ? x : top;
        half_t* outp = (z < 8) ? xT : topT;
        const int b  = z & 7;
        const int r0 = blockIdx.y * 64, c0 = blockIdx.x * 64;
        const float* ib = in + (size_t)b * C_ * T_;
        half_t* ob = outp + (size_t)b * C_ * T_;
        const int t  = threadIdx.x;
        const int rr = t >> 4, cq = t & 15;
        #pragma unroll
        for (int i = 0; i < 4; ++i) {
            const int r = rr + i * 16;
            float4 v = *(const float4*)&ib[(size_t)(r0 + r) * T_ + c0 + cq * 4];
            tile[cq * 4 + 0][r] = v.x;
            tile[cq * 4 + 1][r] = v.y;
            tile[cq * 4 + 2][r] = v.z;
            tile[cq * 4 + 3][r] = v.w;
        }
        __syncthreads();
        const int cw = t >> 4, rq = (t & 15) * 4;
        #pragma unroll
        for (int i = 0; i < 4; ++i) {
            const int c = cw + i * 16;
            half4v h = {(half_t)tile[c][rq + 0], (half_t)tile[c][rq + 1],
                        (half_t)tile[c][rq + 2], (half_t)tile[c][rq + 3]};
            *(half4v*)&ob[(size_t)(c0 + c) * C_ + r0 + rq] = h;
        }
    } else {
        const int n4a = (int)((size_t)B_ * C_ * S_ / 4);
        const int n4tot = n4a + C_ * C_ / 4;
        const int planeT = 32 * 8 * 256;
        for (int i = (blockIdx.y * 32 + blockIdx.x) * 256 + threadIdx.x;
             i < n4tot; i += planeT) {
            const float4* src; half4v* dst; int j;
            if (i < n4a) { src = (const float4*)comb; dst = (half4v*)combh; j = i; }
            else         { src = (const float4*)W;    dst = (half4v*)Wh;    j = i - n4a; }
            float4 v = src[j];
            dst[j] = (half4v){(half_t)v.x, (half_t)v.y, (half_t)v.z, (half_t)v.w};
        }
    }
}

// ---------------------------------------------------------------------------
// GEMM engine v2: BMx256 tile, 8 waves (2Mx4N, per-wave BM/2 x 64), BK=32,
// 4-slot LDS ring, prefetch distance 3 K-tiles, ONE s_barrier + ONE counted
// vmcnt per K-tile (stage issued after the barrier into the slot freed one
// iteration ago), setprio(1) around the MFMA cluster.
// A: [M][K] f16 k-contig.  B: [N][K] f16 k-contig.
// EPI 0 (K1): f16 store of (acc + bias[col] + base[b][col][row])*SCALE
// EPI 1 (k2p): per-256-col-tile softmax prep: p=exp(l-m_tile) f16 + (m,sigma)
// EPI 2 (K4s): B-fragments scaled by f[b][st][n] (LDS-staged); f32 C store
// ---------------------------------------------------------------------------
template<int BM, int MM, int NN, int KK, int EPI>
__global__ __launch_bounds__(512) void gemmv2_kernel(
    const half_t* __restrict__ A, const half_t* __restrict__ Bm,
    size_t sA, size_t sB,
    float* __restrict__ outF, half_t* __restrict__ outH,
    const float* __restrict__ base, const float* __restrict__ bias,
    float* __restrict__ mArr, float* __restrict__ sArr,
    const float* __restrict__ fArr)
{
    constexpr int BN   = 256;
    constexpr int AKT  = BM * 64;            // A bytes per K-tile slot
    constexpr int KTB  = (BM + BN) * 64;     // slot bytes (24KB or 32KB)
    constexpr int RING = 4 * KTB;            // 96KB or 128KB
    constexpr int MI   = BM / 32;            // m-fragments per wave
    constexpr int NT   = KK / 32;
    constexpr int POFF = 256 * 528;          // padded p-tile bytes (EPI1)
    constexpr int LDSSZ = (EPI == 1) ? (POFF + 8192)
                        : (EPI == 2) ? (RING + 8192) : RING;
    static_assert(LDSSZ >= RING || EPI == 1, "ring fit");
    __shared__ __align__(128) char smem[LDSSZ];

    const int tid = threadIdx.x, lane = tid & 63, w = tid >> 6;
    const int wr = w >> 2, wc = w & 3;
    const int fr = lane & 15, kg = lane >> 4, q4 = kg * 4;

    // XCD-pinned flat grid: b = wgid&7
    const int wgid = blockIdx.x;
    const int b = wgid & 7;
    const int tile = wgid >> 3;
    int m0, n0;
    if constexpr (EPI == 2) {  // m-inner: m-blocks sharing a B-panel adjacent
        m0 = (tile % (MM / BM)) * BM;
        n0 = (tile / (MM / BM)) * BN;
    } else {
        n0 = (tile % (NN / BN)) * BN;
        m0 = (tile / (NN / BN)) * BM;
    }

    const half_t* Ab = A  + (size_t)b * sA;
    const half_t* Bb = Bm + (size_t)b * sB;

    // staging geometry: per round 128 rows x 64B; thread t covers
    // row (w*16 + lane>>2), 16B slot (lane&3); src k-slot XOR-swizzled.
    const int rowr = w * 16 + (lane >> 2);
    const int ks8  = (((lane & 3) ^ ((lane >> 2) & 3)) << 3);

    auto STAGE = [&](int t) {
        if (t >= NT) return;
        char* bs = smem + (t & 3) * KTB;
        const int k0 = t * 32;
        #pragma unroll
        for (int r = 0; r < BM / 128; ++r)
            gload_lds16(Ab + (size_t)(m0 + r * 128 + rowr) * KK + k0 + ks8,
                        bs + (r * 128 + w * 16) * 64);
        #pragma unroll
        for (int r = 0; r < BN / 128; ++r)
            gload_lds16(Bb + (size_t)(n0 + r * 128 + rowr) * KK + k0 + ks8,
                        bs + AKT + (r * 128 + w * 16) * 64);
    };

    // fragment ds_read byte offsets within a slot
    int aoff[MI], boff[4];
    #pragma unroll
    for (int mi = 0; mi < MI; ++mi) {
        const int m = wr * (BM / 2) + mi * 16 + fr;
        aoff[mi] = m * 64 + ((kg ^ (m & 3)) << 4);
    }
    #pragma unroll
    for (int nj = 0; nj < 4; ++nj) {
        const int n = wc * 64 + nj * 16 + fr;
        boff[nj] = AKT + n * 64 + ((kg ^ (n & 3)) << 4);
    }

    floatx4 acc[MI][4];
    #pragma unroll
    for (int mi = 0; mi < MI; ++mi)
        #pragma unroll
        for (int nj = 0; nj < 4; ++nj)
            acc[mi][nj] = (floatx4){0.f, 0.f, 0.f, 0.f};

    // prologue: (EPI2) stage f-tile, then 3 K-tiles ahead
    if constexpr (EPI == 2) {
        // f[b][8][n0..n0+256) f32 = 8KB -> smem+RING ; wave w stages st=w row
        gload_lds16(fArr + ((size_t)b * 8 + w) * (size_t)NN + n0 + (lane << 2),
                    smem + RING + w * 1024);
    }
    STAGE(0); STAGE(1); STAGE(2);

    #pragma unroll 1
    for (int t = 0; t < NT; ++t) {
        if constexpr (EPI == 1) {
            asm volatile("s_waitcnt vmcnt(8)" ::: "memory");
        } else {
            asm volatile("s_waitcnt vmcnt(6)" ::: "memory");
        }
        __builtin_amdgcn_s_barrier();
        __builtin_amdgcn_sched_barrier(0);
        STAGE(t + 3);                     // writes slot freed after iter t-1
        __builtin_amdgcn_sched_barrier(0);

        const char* kb = smem + (t & 3) * KTB;
        half8 bf[4];
        #pragma unroll
        for (int nj = 0; nj < 4; ++nj) bf[nj] = *(const half8*)(kb + boff[nj]);
        if constexpr (EPI == 2) {
            const float* fls = (const float*)(smem + RING);
            const int st = t >> 3;        // 256-wide s-tile of this K-chunk
            #pragma unroll
            for (int nj = 0; nj < 4; ++nj) {
                const half_t fh = (half_t)fls[st * 256 + wc * 64 + nj * 16 + fr];
                #pragma unroll
                for (int e = 0; e < 8; ++e) bf[nj][e] *= fh;
            }
        }
        __builtin_amdgcn_s_setprio(1);
        #pragma unroll
        for (int mi = 0; mi < MI; ++mi) {
            half8 af = *(const half8*)(kb + aoff[mi]);
            #pragma unroll
            for (int nj = 0; nj < 4; ++nj)
                acc[mi][nj] = __builtin_amdgcn_mfma_f32_16x16x32_f16(
                    af, bf[nj], acc[mi][nj], 0, 0, 0);
        }
        __builtin_amdgcn_s_setprio(0);
        __builtin_amdgcn_sched_barrier(0);
    }

    // ------------------------------- epilogues -------------------------------
    if constexpr (EPI == 0) {
        half_t* Cb = outH + (size_t)b * ((size_t)MM * NN);
        #pragma unroll
        for (int nj = 0; nj < 4; ++nj) {
            const int col = n0 + wc * 64 + nj * 16 + fr;
            const float bn = bias[col];
            const float* bp = base + ((size_t)b * NN + col) * (size_t)MM;
            #pragma unroll
            for (int mi = 0; mi < MI; ++mi) {
                const int row = m0 + wr * (BM / 2) + mi * 16 + q4;
                #pragma unroll
                for (int r = 0; r < 4; ++r) {
                    float v = (acc[mi][nj][r] + bn + bp[row + r]) * SCALE_WEIGHT;
                    Cb[(size_t)(row + r) * NN + col] = (half_t)v;
                }
            }
        }
    } else if constexpr (EPI == 2) {
        float* Cb = outF + (size_t)b * ((size_t)MM * NN);
        #pragma unroll
        for (int mi = 0; mi < MI; ++mi) {
            const int row = m0 + wr * (BM / 2) + mi * 16 + q4;
            #pragma unroll
            for (int nj = 0; nj < 4; ++nj) {
                const int col = n0 + wc * 64 + nj * 16 + fr;
                #pragma unroll
                for (int r = 0; r < 4; ++r)
                    Cb[(size_t)(row + r) * NN + col] = acc[mi][nj][r];
            }
        }
    } else {
        // k2p: per-tile row-max, p=exp(l-m) -> padded LDS tile (stride 528B),
        // stats out, coalesced half8 p stores. Ring is dead: quiesce & reuse.
        asm volatile("s_waitcnt vmcnt(0)" ::: "memory");
        __syncthreads();
        float* rmax = (float*)(smem + POFF);          // [4][256]
        float* rsum = rmax + 1024;                    // [4][256]

        #pragma unroll
        for (int mi = 0; mi < MI; ++mi)
            #pragma unroll
            for (int r = 0; r < 4; ++r) {
                float v = fmaxf(fmaxf(acc[mi][0][r], acc[mi][1][r]),
                                fmaxf(acc[mi][2][r], acc[mi][3][r]));
                v = fmaxf(v, __shfl_xor(v, 1));
                v = fmaxf(v, __shfl_xor(v, 2));
                v = fmaxf(v, __shfl_xor(v, 4));
                v = fmaxf(v, __shfl_xor(v, 8));
                if (fr == 0)
                    rmax[wc * 256 + wr * 128 + mi * 16 + q4 + r] = v;
            }
        __syncthreads();

        #pragma unroll
        for (int mi = 0; mi < MI; ++mi)
            #pragma unroll
            for (int r = 0; r < 4; ++r) {
                const int row = wr * 128 + mi * 16 + q4 + r;
                const float mC = fmaxf(fmaxf(rmax[row], rmax[256 + row]),
                                       fmaxf(rmax[512 + row], rmax[768 + row]));
                float s = 0.f;
                #pragma unroll
                for (int nj = 0; nj < 4; ++nj) {
                    const int col = wc * 64 + nj * 16 + fr;
                    float pv = __expf(acc[mi][nj][r] - mC);
                    s += pv;
                    *(half_t*)(smem + row * 528 + col * 2) = (half_t)pv;
                }
                s += __shfl_xor(s, 1);
                s += __shfl_xor(s, 2);
                s += __shfl_xor(s, 4);
                s += __shfl_xor(s, 8);
                if (fr == 0) rsum[wc * 256 + row] = s;
            }
        __syncthreads();

        if (tid < 256) {
            const float m = fmaxf(fmaxf(rmax[tid], rmax[256 + tid]),
                                  fmaxf(rmax[512 + tid], rmax[768 + tid]));
            const float s = rsum[tid] + rsum[256 + tid] +
                            rsum[512 + tid] + rsum[768 + tid];
            const size_t si = ((size_t)(b * 8 + (n0 >> 8))) * (size_t)MM + m0 + tid;
            mArr[si] = m;
            sArr[si] = s;
        }

        const int prow = tid >> 1, ph = tid & 1;
        const size_t gb = ((size_t)b * MM + m0 + prow) * (size_t)NN + n0 + ph * 128;
        #pragma unroll
        for (int j = 0; j < 16; ++j) {
            half8 v = *(const half8*)(smem + prow * 528 + ph * 256 + j * 16);
            *(half8*)&outH[gb + j * 8] = v;
        }
    }
}

// ---------------------------------------------------------------------------
// kf: f[b][st][t] = exp(m_st - m_fin) / sigma  (exact tile-stat combine, 8 st)
// ---------------------------------------------------------------------------
__global__ __launch_bounds__(256) void kf_kernel(
    const float* __restrict__ mArr, const float* __restrict__ sArr,
    float* __restrict__ fArr)
{
    const int gid = blockIdx.x * 256 + threadIdx.x;   // b*2048 + t
    const int b = gid >> 11, t = gid & 2047;
    float mv[8];
    float mfin = -3.0e38f;
    #pragma unroll
    for (int j = 0; j < 8; ++j) {
        mv[j] = mArr[((size_t)(b * 8 + j)) * T_ + t];
        mfin = fmaxf(mfin, mv[j]);
    }
    float sig = 0.f;
    #pragma unroll
    for (int j = 0; j < 8; ++j)
        sig += sArr[((size_t)(b * 8 + j)) * T_ + t] * __expf(mv[j] - mfin);
    const float inv = 1.f / sig;
    #pragma unroll
    for (int j = 0; j < 8; ++j)
        fArr[((size_t)(b * 8 + j)) * T_ + t] = __expf(mv[j] - mfin) * inv;
}

// ---------------------------------------------------------------------------
// k3n: attnf[b][t][s] = p[b][t][s] * f[b][s>>8][t]   (f32 attn output)
// ---------------------------------------------------------------------------
__global__ __launch_bounds__(256) void k3n_kernel(
    const half_t* __restrict__ P, const float* __restrict__ fArr,
    float* __restrict__ attnf)
{
    const int bid = blockIdx.x;           // b*2048 + t
    const int b = bid >> 11, t = bid & 2047;
    const int tid = threadIdx.x;
    const float f = fArr[((size_t)(b * 8 + (tid >> 5))) * T_ + t];
    const size_t rb = (size_t)bid * S_ + tid * 8;
    half8 v = *(const half8*)&P[rb];
    float4 o0 = {(float)v[0] * f, (float)v[1] * f, (float)v[2] * f, (float)v[3] * f};
    float4 o1 = {(float)v[4] * f, (float)v[5] * f, (float)v[6] * f, (float)v[7] * f};
    *(float4*)&attnf[rb]     = o0;
    *(float4*)&attnf[rb + 4] = o1;
}

extern "C" void kernel_launch(void* const* d_in, const int* in_sizes, int n_in,
                              void* d_out, int out_size, void* d_ws, size_t ws_size,
                              hipStream_t stream) {
    const float* base = (const float*)d_in[0];  // [B,C,T,1]
    const float* x    = (const float*)d_in[1];  // [B,C,T,1]
    const float* top  = (const float*)d_in[2];  // [B,C,S]
    const float* comb = (const float*)d_in[3];  // [B,C,S]
    const float* W    = (const float*)d_in[4];  // [C,C]
    const float* bias = (const float*)d_in[5];  // [C]

    float* out   = (float*)d_out;
    float* ctx   = out;          // [B,C,T] final context output (f32, 33.5MB)
    float* attnf = out + BCT_;   // [B,T,S] attn output (f32, 134MB)

    // fp16 staging overlaid on the ctx region (dead before K4s rewrites it):
    half_t* xT   = (half_t*)d_out;        // [B][T][C] f16
    half_t* topT = xT + BCT_;             // [B][S][C] f16

    // ws layout (~103MB):
    half_t* pws   = (half_t*)d_ws;                    // [B][T][S] f16, 67MB
    half_t* combh = pws + BTS_;                       // [B][C][S] f16, 16.8MB
    half_t* Wh    = combh + (size_t)B_ * C_ * S_;     // [C][C] f16, 0.5MB
    half_t* tgtT  = Wh + (size_t)C_ * C_;             // [B][T][C] f16, 16.8MB
    float*  mArr  = (float*)(tgtT + BCT_);            // [B][8][T] f32
    float*  sArr  = mArr + (size_t)B_ * 8 * T_;       // [B][8][T] f32
    float*  fArr  = sArr + (size_t)B_ * 8 * T_;       // [B][8][T] f32

    // pre-pass (1 launch): transposes + converts
    pre_kernel<<<dim3(32, 8, 17), 256, 0, stream>>>(
        x, top, comb, W, xT, topT, combh, Wh);

    // K1: tgtT[b][t][o] = (x^T W^T + b + base)*SCALE   M=T,N=C=512,K=C (sB=0)
    gemmv2_kernel<128, 2048, 512, 512, 0><<<256, 512, 0, stream>>>(
        xT, Wh, (size_t)T_ * C_, 0,
        nullptr, tgtT, base, bias, nullptr, nullptr, nullptr);

    // k2p: p = exp(logits - m_tile) f16 + per-256-tile stats   M=T,N=S,K=C
    gemmv2_kernel<256, 2048, 2048, 512, 1><<<512, 512, 0, stream>>>(
        tgtT, topT, (size_t)T_ * C_, (size_t)S_ * C_,
        nullptr, pws, nullptr, nullptr, mArr, sArr, nullptr);

    // kf: exact stat combine -> f[b][st][t]
    kf_kernel<<<64, 256, 0, stream>>>(mArr, sArr, fArr);

    // k3n: attnf = p * f  (f32 attn output)
    k3n_kernel<<<B_ * T_, 256, 0, stream>>>(pws, fArr, attnf);

    // K4s: ctx[b][c][t] = sum_s comb[c][s] * (p[t][s]*f[st][t])  M=C,N=T,K=S
    gemmv2_kernel<128, 512, 2048, 2048, 2><<<256, 512, 0, stream>>>(
        combh, pws, (size_t)C_ * S_, (size_t)T_ * S_,
        ctx, nullptr, nullptr, nullptr, nullptr, nullptr, fArr);
}